// Round 2
// baseline (1343.446 us; speedup 1.0000x reference)
//
#include <hip/hip_runtime.h>
#include <math.h>

// B=1024, S=512, H=512, D=2048
// Two-pass structure:
//  Pass 1 (sem_pass): globally-interleaved grid-stride over all B*S token rows.
//    Wave g handles tokens g, g+NW, g+2NW, ... (NW = total waves) so the whole
//    grid sweeps hidden_states as ONE dense frontier (copy-kernel access shape),
//    instead of 1024 block-private 1MB streams. Per token: 2x 1KB coalesced
//    loads, 64-lane butterfly, lane0 stores sigmoid(dot+pb) to workspace.
//  Pass 2 (fuse_pass): per-b reduce of the 512 sigmoids + eigen score + scalar
//    fusion. ~12 MB traffic total, trivial.

#define S_TOK 512
#define H_DIM 512
#define D_DIM 2048
#define H4    (H_DIM / 4)

__device__ __forceinline__ float sigmoidf_fast(float x) {
    return 1.0f / (1.0f + __expf(-x));
}
__device__ __forceinline__ float dot4(float4 a, float4 b) {
    return a.x * b.x + a.y * b.y + a.z * b.z + a.w * b.w;
}

__global__ __launch_bounds__(256, 4) void sem_pass(
    const float* __restrict__ hidden_states,
    const float* __restrict__ probe_w,
    const float* __restrict__ probe_b,
    float* __restrict__ tok_sig,
    int total_tokens)
{
    const int lane = threadIdx.x & 63;
    const int wave = threadIdx.x >> 6;
    const int gw   = blockIdx.x * 4 + wave;   // global wave id
    const int nw   = gridDim.x * 4;           // total waves

    // probe weights register-resident: 8 data VGPRs
    const float4* pw4 = (const float4*)probe_w;
    const float4 w0 = pw4[lane];
    const float4 w1 = pw4[lane + 64];
    const float  pb = probe_b[0];

    const float4* hs4 = (const float4*)hidden_states;

    // two tokens per step -> 4KB in flight per wave, independent reduce chains
    for (int t = gw; t < total_tokens; t += 2 * nw) {
        const float4* r0 = hs4 + (size_t)t * H4;
        const float4 a0 = r0[lane];
        const float4 a1 = r0[lane + 64];

        const int t2 = t + nw;
        float4 b0 = make_float4(0.f, 0.f, 0.f, 0.f);
        float4 b1 = make_float4(0.f, 0.f, 0.f, 0.f);
        if (t2 < total_tokens) {
            const float4* r1 = hs4 + (size_t)t2 * H4;
            b0 = r1[lane];
            b1 = r1[lane + 64];
        }

        float d = dot4(a0, w0) + dot4(a1, w1);
        float e = dot4(b0, w0) + dot4(b1, w1);
        #pragma unroll
        for (int m = 32; m > 0; m >>= 1) {
            d += __shfl_xor(d, m, 64);
            e += __shfl_xor(e, m, 64);
        }
        if (lane == 0) {
            tok_sig[t] = sigmoidf_fast(d + pb);
            if (t2 < total_tokens) tok_sig[t2] = sigmoidf_fast(e + pb);
        }
    }
}

__global__ __launch_bounds__(256) void fuse_pass(
    const float* __restrict__ routing_entropy,
    const float* __restrict__ moe_confidence,
    const float* __restrict__ memory_mismatch,
    const float* __restrict__ routing_repr,
    const float* __restrict__ tok_sig,
    float* __restrict__ out)
{
    const int b    = blockIdx.x;
    const int tid  = threadIdx.x;
    const int lane = tid & 63;
    const int wave = tid >> 6;

    // semantic mean: 512 sigmoids, 2 per thread
    const float* ts = tok_sig + (size_t)b * S_TOK;
    float sem = ts[tid] + ts[tid + 256];

    // eigen score: sum of squares of routing_repr[b, 0:2048]
    const float4* rr4 = (const float4*)(routing_repr + (size_t)b * D_DIM);
    const float4 r0 = rr4[tid];
    const float4 r1 = rr4[tid + 256];
    float sq = dot4(r0, r0) + dot4(r1, r1);

    #pragma unroll
    for (int m = 32; m > 0; m >>= 1) {
        sem += __shfl_xor(sem, m, 64);
        sq  += __shfl_xor(sq,  m, 64);
    }

    __shared__ float s_sem[4];
    __shared__ float s_sq[4];
    if (lane == 0) { s_sem[wave] = sem; s_sq[wave] = sq; }
    __syncthreads();

    if (tid == 0) {
        const float sem_mean = (s_sem[0] + s_sem[1] + s_sem[2] + s_sem[3]) * (1.0f / S_TOK);
        const float sv       = sqrtf(s_sq[0] + s_sq[1] + s_sq[2] + s_sq[3]);
        const float neig     = sigmoidf_fast(1.0f / (sv + 1e-8f) - 1.0f);

        const float ne = routing_entropy[b] * 0.48089834696298783f;  // 1/ln(8)
        const float ic = 1.0f - moe_confidence[b];
        const float nm = sigmoidf_fast(memory_mismatch[b] - 2.0f);

        float risk = 0.25f * ne - 0.2f * ic + 0.2f * nm
                   + 0.2f * sem_mean + 0.15f * neig;
        risk = fminf(fmaxf(risk, 0.0f), 1.0f);
        out[b] = risk;
    }
}

extern "C" void kernel_launch(void* const* d_in, const int* in_sizes, int n_in,
                              void* d_out, int out_size, void* d_ws, size_t ws_size,
                              hipStream_t stream) {
    const float* routing_entropy = (const float*)d_in[0];
    const float* moe_confidence  = (const float*)d_in[1];
    const float* memory_mismatch = (const float*)d_in[2];
    // d_in[3] = memory_loss (unused by reference)
    const float* hidden_states   = (const float*)d_in[4];
    const float* routing_repr    = (const float*)d_in[5];
    const float* probe_w         = (const float*)d_in[6];
    const float* probe_b         = (const float*)d_in[7];
    float* out = (float*)d_out;

    const int B = in_sizes[0];  // 1024
    const int total_tokens = B * S_TOK;

    float* tok_sig = (float*)d_ws;  // B*S floats = 2 MB, well under ws_size

    sem_pass<<<4096, 256, 0, stream>>>(hidden_states, probe_w, probe_b,
                                       tok_sig, total_tokens);
    fuse_pass<<<B, 256, 0, stream>>>(routing_entropy, moe_confidence,
                                     memory_mismatch, routing_repr,
                                     tok_sig, out);
}